// Round 9
// baseline (308.000 us; speedup 1.0000x reference)
//
#include <hip/hip_runtime.h>

#define T_DIM 8192
#define D_DIM 256
#define N_DIM 64
#define LOG2E 1.44269504f

typedef __bf16 bf16x8 __attribute__((ext_vector_type(8)));
typedef __bf16 bf16x4 __attribute__((ext_vector_type(4)));
typedef float f32x16 __attribute__((ext_vector_type(16)));

__device__ __forceinline__ f32x16 zero16() {
  f32x16 v;
#pragma unroll
  for (int i = 0; i < 16; ++i) v[i] = 0.f;
  return v;
}

// ---------------------------------------------------------------------------
// Device barrier for 512 co-resident blocks, R5-PROVEN protocol (counters
// zeroed per launch by hipMemsetAsync -- immune to workspace poisoning).
// Slot layout (16 uints): [0]=root, [1]=flag, [2..9]=8 sub-counters.
// Arrive: bump sub (bx&7); 64th bumps root; 8th root sets flag=1.
// Spin on flag==0: a block arriving after the flag is set falls through
// immediately -- no epoch race, deadlock-free. (R8's memset-free epoch
// variant deadlocked under poisoned ws: arbitrary c0 => early flag bump =>
// late arrivals spin forever.)
// ---------------------------------------------------------------------------
__device__ __forceinline__ void gbar(unsigned int* slot) {
  __syncthreads();
  if (threadIdx.x == 0) {
    __threadfence();  // release: flush this block's writes
    unsigned int o = __hip_atomic_fetch_add(&slot[2 + (blockIdx.x & 7)], 1u,
                                            __ATOMIC_ACQ_REL,
                                            __HIP_MEMORY_SCOPE_AGENT);
    if (o == 63u) {
      unsigned int r = __hip_atomic_fetch_add(&slot[0], 1u, __ATOMIC_ACQ_REL,
                                              __HIP_MEMORY_SCOPE_AGENT);
      if (r == 7u)
        __hip_atomic_store(&slot[1], 1u, __ATOMIC_RELEASE,
                           __HIP_MEMORY_SCOPE_AGENT);
    }
    while (__hip_atomic_load(&slot[1], __ATOMIC_RELAXED,
                             __HIP_MEMORY_SCOPE_AGENT) == 0u)
      __builtin_amdgcn_s_sleep(2);
    __threadfence();  // acquire: invalidate stale lines
  }
  __syncthreads();
}

// DHf: fragment-major. Row-group G=t>>5, chunk c=kk*2+h, lane l31:
// DHf[G*2048 + c*256 + l31*8 .. +7] = DH[n=c*8+e][t=G*32+l31].

// ---------------------------------------------------------------------------
// K_FRONT (512 blocks x 512 thr, co-resident at 2 blk/CU):
//   Phase A (blocks 0..127, waves 0..3): DHf + lbe + rowsum=0 via the
//     R5-proven slim-LDS variant (direct column-coalesced H loads, 9KB DHs).
//   gbar
//   Phase B (all 512): k_rowsum -- EXACT R3-proven body at its native
//     geometry (512x512thr, 33.8KB LDS).
// ---------------------------------------------------------------------------
__global__ __launch_bounds__(512, 4) void k_front(
    const float* __restrict__ H, const float* __restrict__ Dm,
    __bf16* __restrict__ DHf, float* __restrict__ lbe,
    float* __restrict__ rowsum, unsigned int* __restrict__ bar) {
  __shared__ union {
    __bf16 DHs[64 * 72];   // 9.2 KB (phase A)
    float red2[256][33];   // 33.8 KB (phase B)
  } sm;
  const int tid = threadIdx.x;
  const int bx = (int)blockIdx.x;
  const int lane = tid & 63;
  const int wave = tid >> 6;  // 0..7
  const int h = lane >> 5;
  const int l31 = lane & 31;

  // ========================= Phase A =========================
  if (bx < 128) {
    const int t0 = bx * 64;
    if (wave < 4) {
      const int tt = wave & 1, nh = wave >> 1;
      const int m = tt * 32 + l31;
      const int n = nh * 32 + l31;
      f32x16 c = zero16();
      for (int kk = 0; kk < 16; ++kk) {
        float av[8];
#pragma unroll
        for (int e = 0; e < 8; ++e)
          av[e] = H[(size_t)(kk * 16 + h * 8 + e) * T_DIM + t0 + m];
        bf16x8 ahi, alo;
#pragma unroll
        for (int e = 0; e < 8; ++e) {
          __bf16 hi = (__bf16)av[e];
          ahi[e] = hi;
          alo[e] = (__bf16)(av[e] - (float)hi);
        }
        const float4* dp =
            (const float4*)(Dm + (size_t)n * 256 + kk * 16 + h * 8);
        float4 b0 = dp[0], b1 = dp[1];
        float bv[8] = {b0.x, b0.y, b0.z, b0.w, b1.x, b1.y, b1.z, b1.w};
        bf16x8 bhi, blo;
#pragma unroll
        for (int i = 0; i < 8; ++i) {
          __bf16 hi = (__bf16)bv[i];
          bhi[i] = hi;
          blo[i] = (__bf16)(bv[i] - (float)hi);
        }
        c = __builtin_amdgcn_mfma_f32_32x32x16_bf16(ahi, bhi, c, 0, 0, 0);
        c = __builtin_amdgcn_mfma_f32_32x32x16_bf16(ahi, blo, c, 0, 0, 0);
        c = __builtin_amdgcn_mfma_f32_32x32x16_bf16(alo, bhi, c, 0, 0, 0);
      }
#pragma unroll
      for (int r = 0; r < 16; ++r) {
        int row = tt * 32 + (r & 3) + 8 * (r >> 2) + 4 * h;
        sm.DHs[row * 72 + n] = (__bf16)c[r];
      }
    }
    __syncthreads();
    {  // export: 512 threads cover g(2) x cc(8) x l(32) exactly once
      int g = tid >> 8, cc = (tid >> 5) & 7, l = tid & 31;
      bf16x8 w = *(const bf16x8*)&sm.DHs[(g * 32 + l) * 72 + cc * 8];
      *(bf16x8*)(DHf + (size_t)(bx * 2 + g) * 2048 + cc * 256 + l * 8) = w;
    }
    if (tid < 64) {
      float s = 0.f;
#pragma unroll
      for (int q = 0; q < 8; ++q) {
        bf16x8 w = *(const bf16x8*)&sm.DHs[tid * 72 + q * 8];
#pragma unroll
        for (int i = 0; i < 8; ++i) { float f = (float)w[i]; s += f * f; }
      }
      lbe[t0 + tid] = -0.5f * s * LOG2E;
      rowsum[t0 + tid] = 0.f;
    }
  }
  gbar(bar + 0);

  // ========================= Phase B (R3-proven body) ========================
  {
    const int t0 = (bx >> 4) * 256;
    const int jbase = (bx & 15) * 512;
    const size_t Gt = (size_t)(t0 >> 5) + wave;
    bf16x8 aR[4];
#pragma unroll
    for (int kk = 0; kk < 4; ++kk)
      aR[kk] = *(const bf16x8*)(DHf + Gt * 2048 + kk * 512 + lane * 8);
    float racc[16];
#pragma unroll
    for (int r = 0; r < 16; ++r) racc[r] = 0.f;
    bf16x8 b[4];
    {
      const size_t Gj = (size_t)(jbase >> 5);
#pragma unroll
      for (int kk = 0; kk < 4; ++kk)
        b[kk] = *(const bf16x8*)(DHf + Gj * 2048 + kk * 512 + lane * 8);
    }
    for (int jit = 0; jit < 16; ++jit) {
      bf16x8 bn[4];
      if (jit < 15) {
        const size_t Gj = (size_t)(jbase >> 5) + jit + 1;
#pragma unroll
        for (int kk = 0; kk < 4; ++kk)
          bn[kk] = *(const bf16x8*)(DHf + Gj * 2048 + kk * 512 + lane * 8);
      }
      const float lbv = lbe[jbase + jit * 32 + l31];
      f32x16 s = zero16();
      s = __builtin_amdgcn_mfma_f32_32x32x16_bf16(aR[0], b[0], s, 0, 0, 0);
      s = __builtin_amdgcn_mfma_f32_32x32x16_bf16(aR[1], b[1], s, 0, 0, 0);
      s = __builtin_amdgcn_mfma_f32_32x32x16_bf16(aR[2], b[2], s, 0, 0, 0);
      s = __builtin_amdgcn_mfma_f32_32x32x16_bf16(aR[3], b[3], s, 0, 0, 0);
#pragma unroll
      for (int r = 0; r < 16; ++r)
        racc[r] += __builtin_amdgcn_exp2f(__builtin_fmaf(s[r], LOG2E, lbv));
      if (jit < 15) {
#pragma unroll
        for (int kk = 0; kk < 4; ++kk) b[kk] = bn[kk];
      }
    }
#pragma unroll
    for (int r = 0; r < 16; ++r) {
      int tl = wave * 32 + (r & 3) + 8 * (r >> 2) + 4 * h;
      sm.red2[tl][l31] = racc[r];
    }
    __syncthreads();
    if (tid < 256) {
      float s = 0.f;
#pragma unroll 8
      for (int c = 0; c < 32; ++c) s += sm.red2[tid][c];
      atomicAdd(&rowsum[t0 + tid], s);
    }
  }
}

// ---------------------------------------------------------------------------
// K_BACK (512 blocks x 256 thr, 2 blk/CU, 64KB LDS):
//   Phase C: Hbf_sw = bf16(H*rinv) pre-swizzled (R4 scaleH split over 512).
//   gbar
//   Phase D: EXACT R4-proven k_z (61.4us): dbuf Hs/Pt, aR/aRn, setprio,
//            coalesced plane stores.
//   gbar
//   Phase E: Z = l2*sum planes -- grid-wide balanced (R7 lesson).
// ---------------------------------------------------------------------------
__global__ __launch_bounds__(256, 2) void k_back(
    const float* __restrict__ H, const __bf16* __restrict__ DHf,
    const float* __restrict__ lbe, const float* __restrict__ rowsum,
    const float* __restrict__ l2p, __bf16* __restrict__ Hbf_sw,
    float* __restrict__ Zp, float* __restrict__ Z,
    unsigned int* __restrict__ bar) {
  __shared__ __bf16 Hs[2][128 * 64];  // [dl][t] swizzled, 2 x 16 KB
  __shared__ __bf16 Pt[2][128 * 64];  // [j][t] swizzled,  2 x 16 KB
  const int tid = threadIdx.x;
  const int lane = tid & 63;
  const int wave = tid >> 6;
  const int h = lane >> 5;
  const int l31 = lane & 31;
  const int bx = (int)blockIdx.x;

  // ========================= Phase C =========================
  {
    float* rinvL = (float*)&Hs[0][0];  // 256B LDS scratch (dead before D)
    const int u = bx >> 1;
    const int tblk = u >> 1, dhc = u & 1;
    const int half = bx & 1;
    const int t0c = tblk * 64;
    if (tid < 64) rinvL[tid] = 1.0f / rowsum[t0c + tid];
    __syncthreads();
#pragma unroll
    for (int ii = 0; ii < 2; ++ii) {
      int itr = half * 2 + ii;
      int idx = itr * 256 + tid;
      int dl = idx >> 3, tbp = idx & 7;
      int d = dhc * 128 + dl;
      int swz = (d ^ (d >> 3)) & 7;
      int tloc = (tbp ^ swz) << 3;
      const float4* hp = (const float4*)(H + (size_t)d * T_DIM + t0c + tloc);
      float4 v0 = hp[0], v1 = hp[1];
      float4 r0 = *(const float4*)&rinvL[tloc];
      float4 r1 = *(const float4*)&rinvL[tloc + 4];
      bf16x8 w;
      w[0] = (__bf16)(v0.x * r0.x); w[1] = (__bf16)(v0.y * r0.y);
      w[2] = (__bf16)(v0.z * r0.z); w[3] = (__bf16)(v0.w * r0.w);
      w[4] = (__bf16)(v1.x * r1.x); w[5] = (__bf16)(v1.y * r1.y);
      w[6] = (__bf16)(v1.z * r1.z); w[7] = (__bf16)(v1.w * r1.w);
      *(bf16x8*)(Hbf_sw + (size_t)tblk * 16384 + (size_t)d * 64 + tbp * 8) = w;
    }
  }
  gbar(bar + 16);

  // ========================= Phase D (R4-proven k_z body) ====================
  {
    const int ts = bx & 3;
    const int dh = (bx >> 2) & 1;
    const int j0 = (bx >> 3) * 128;
    const int s_tt = wave & 1, s_jg = wave >> 1;
    bf16x8 bS[2][4];
    float lbv[2];
#pragma unroll
    for (int q = 0; q < 2; ++q) {
      const size_t Gj = (j0 >> 5) + s_jg * 2 + q;
#pragma unroll
      for (int kk = 0; kk < 4; ++kk)
        bS[q][kk] = *(const bf16x8*)(DHf + Gj * 2048 + kk * 512 + lane * 8);
      lbv[q] = lbe[j0 + (s_jg * 2 + q) * 32 + l31];
    }
    f32x16 acc[2][2];
#pragma unroll
    for (int u = 0; u < 2; ++u)
#pragma unroll
      for (int v = 0; v < 2; ++v) acc[u][v] = zero16();

#define DMA_HS(buf_, it_)                                                       \
  {                                                                             \
    const __bf16* gsrc =                                                        \
        Hbf_sw + (size_t)(ts * 32 + (it_)) * 16384 + (size_t)dh * 8192;         \
    _Pragma("unroll") for (int r = 0; r < 4; ++r) {                             \
      int chunk = wave * 4 + r;                                                 \
      __builtin_amdgcn_global_load_lds(                                         \
          (const __attribute__((address_space(1))) unsigned int*)(gsrc +        \
              chunk * 512 + lane * 8),                                          \
          (__attribute__((address_space(3))) unsigned int*)(&Hs[buf_][0] +      \
              chunk * 512),                                                     \
          16, 0, 0);                                                            \
    }                                                                           \
  }

#define LOAD_AR(reg_, n_)                                                       \
  {                                                                             \
    const size_t Gt_ = (size_t)(ts * 64 + (n_)*2 + s_tt);                       \
    _Pragma("unroll") for (int kk = 0; kk < 4; ++kk)                            \
        (reg_)[kk] = *(const bf16x8*)(DHf + Gt_ * 2048 + kk * 512 + lane * 8);  \
  }

#define S_PHASE(p_, reg_)                                                       \
  {                                                                             \
    _Pragma("unroll") for (int q = 0; q < 2; ++q) {                             \
      f32x16 s = zero16();                                                      \
      _Pragma("unroll") for (int kk = 0; kk < 4; ++kk)                          \
          s = __builtin_amdgcn_mfma_f32_32x32x16_bf16((reg_)[kk], bS[q][kk], s, \
                                                      0, 0, 0);                 \
      const int jl = (s_jg * 2 + q) * 32 + l31;                                 \
      const int sj = (jl ^ (jl >> 3)) & 7;                                      \
      _Pragma("unroll") for (int g = 0; g < 4; ++g) {                           \
        const int tl = s_tt * 32 + g * 8 + 4 * h;                               \
        bf16x4 pv;                                                              \
        pv[0] = (__bf16)__builtin_amdgcn_exp2f(                                 \
            __builtin_fmaf(s[g * 4 + 0], LOG2E, lbv[q]));                       \
        pv[1] = (__bf16)__builtin_amdgcn_exp2f(                                 \
            __builtin_fmaf(s[g * 4 + 1], LOG2E, lbv[q]));                       \
        pv[2] = (__bf16)__builtin_amdgcn_exp2f(                                 \
            __builtin_fmaf(s[g * 4 + 2], LOG2E, lbv[q]));                       \
        pv[3] = (__bf16)__builtin_amdgcn_exp2f(                                 \
            __builtin_fmaf(s[g * 4 + 3], LOG2E, lbv[q]));                       \
        const int cchunk = tl >> 3;                                             \
        *(bf16x4*)&Pt[p_][jl * 64 + ((cchunk ^ sj) << 3) + 4 * h] = pv;         \
      }                                                                         \
    }                                                                           \
  }

#define Z_PHASE(p_)                                                             \
  {                                                                             \
    __builtin_amdgcn_s_setprio(1);                                              \
    _Pragma("unroll") for (int kk = 0; kk < 4; ++kk) {                          \
      const int c = kk * 2 + h;                                                 \
      bf16x8 af[2], bw[2];                                                      \
      _Pragma("unroll") for (int u = 0; u < 2; ++u) {                           \
        int dl = (wave & 1) * 64 + u * 32 + l31;                                \
        af[u] =                                                                 \
            *(const bf16x8*)&Hs[p_][dl * 64 + ((c ^ ((dl ^ (dl >> 3)) & 7)) << 3)]; \
      }                                                                         \
      _Pragma("unroll") for (int v = 0; v < 2; ++v) {                           \
        int j = (wave >> 1) * 64 + v * 32 + l31;                                \
        bw[v] =                                                                 \
            *(const bf16x8*)&Pt[p_][j * 64 + ((c ^ ((j ^ (j >> 3)) & 7)) << 3)]; \
      }                                                                         \
      _Pragma("unroll") for (int u = 0; u < 2; ++u)                             \
          _Pragma("unroll") for (int v = 0; v < 2; ++v)                         \
              acc[u][v] = __builtin_amdgcn_mfma_f32_32x32x16_bf16(              \
                  af[u], bw[v], acc[u][v], 0, 0, 0);                            \
    }                                                                           \
    __builtin_amdgcn_s_setprio(0);                                              \
  }

    bf16x8 aR[4], aRn[4];
    LOAD_AR(aR, 0);
    DMA_HS(0, 0);
    S_PHASE(0, aR);
    LOAD_AR(aRn, 1);
    __syncthreads();

    for (int ii = 0; ii < 16; ++ii) {
      const int it0 = ii * 2;
      DMA_HS(1, it0 + 1);
      if (it0 < 30) LOAD_AR(aR, it0 + 2);
      S_PHASE(1, aRn);
      Z_PHASE(0);
      __syncthreads();
      if (it0 + 1 < 31) {
        DMA_HS(0, it0 + 2);
        S_PHASE(0, aR);
      }
      if (it0 + 1 < 30) LOAD_AR(aRn, it0 + 3);
      Z_PHASE(1);
      __syncthreads();
    }
#undef Z_PHASE
#undef S_PHASE
#undef LOAD_AR
#undef DMA_HS
    float* zp = Zp + (size_t)ts * (256 * (size_t)T_DIM);
#pragma unroll
    for (int u = 0; u < 2; ++u)
#pragma unroll
      for (int v = 0; v < 2; ++v)
#pragma unroll
        for (int r = 0; r < 16; ++r) {
          int d = dh * 128 + (wave & 1) * 64 + u * 32 + (r & 3) + 8 * (r >> 2) + 4 * h;
          int j = j0 + (wave >> 1) * 64 + v * 32 + l31;
          zp[(size_t)d * T_DIM + j] = acc[u][v][r];
        }
  }
  gbar(bar + 32);

  // ========================= Phase E (balanced, R5-proven body) ==============
  {
    const float l2v = l2p[0];
    const float4* zp4 = (const float4*)Zp;
    float4* Z4 = (float4*)Z;
#pragma unroll
    for (int k = 0; k < 4; ++k) {
      int i = k * 131072 + bx * 256 + tid;
      float4 a = zp4[i];
#pragma unroll
      for (int s = 1; s < 4; ++s) {
        float4 b = zp4[(size_t)s * 524288 + i];
        a.x += b.x; a.y += b.y; a.z += b.z; a.w += b.w;
      }
      float4 o = {a.x * l2v, a.y * l2v, a.z * l2v, a.w * l2v};
      Z4[i] = o;
    }
  }
}

// ---------------------------------------------------------------------------
extern "C" void kernel_launch(void* const* d_in, const int* in_sizes, int n_in,
                              void* d_out, int out_size, void* d_ws,
                              size_t ws_size, hipStream_t stream) {
  (void)in_sizes; (void)n_in; (void)out_size; (void)ws_size;
  const float* H = (const float*)d_in[0];
  const float* Dm = (const float*)d_in[1];
  const float* l2 = (const float*)d_in[2];
  float* Z = (float*)d_out;
  char* ws = (char*)d_ws;
  __bf16* DHf = (__bf16*)ws;                          // 1,048,576 B
  float* lbe = (float*)(ws + 1048576);                // 32,768 B
  float* rowsum = (float*)(ws + 1081344);             // 32,768 B
  unsigned int* bar = (unsigned int*)(ws + 1114112);  // 256 B (3 slots x 64B)
  __bf16* Hbf_sw = (__bf16*)(ws + 1118208);           // 4,194,304 B
  float* Zp = (float*)(ws + 5312512);                 // 33,554,432 B

  hipMemsetAsync(ws + 1114112, 0, 256, stream);
  k_front<<<512, 512, 0, stream>>>(H, Dm, DHf, lbe, rowsum, bar);
  k_back<<<512, 256, 0, stream>>>(H, DHf, lbe, rowsum, l2, Hbf_sw, Zp, Z, bar);
}

// Round 10
// 147.044 us; speedup vs baseline: 2.0946x; 2.0946x over previous
//
#include <hip/hip_runtime.h>

#define T_DIM 8192
#define D_DIM 256
#define N_DIM 64
#define LOG2E 1.44269504f

typedef __bf16 bf16x8 __attribute__((ext_vector_type(8)));
typedef __bf16 bf16x4 __attribute__((ext_vector_type(4)));
typedef float f32x16 __attribute__((ext_vector_type(16)));

__device__ __forceinline__ f32x16 zero16() {
  f32x16 v;
#pragma unroll
  for (int i = 0; i < 16; ++i) v[i] = 0.f;
  return v;
}

// DHf: fragment-major. Row-group G=t>>5, chunk c=kk*2+h, lane l31:
// DHf[G*2048 + c*256 + l31*8 .. +7] = DH[n=c*8+e][t=G*32+l31].

// ---------------------------------------------------------------------------
// K1: DHf (bf16, fragment-major) via split-bf16 MFMA, lbe[t]=lb*log2e,
//     rowsum[t]=0. grid 128 x 256.  (R4-proven, byte-identical)
// ---------------------------------------------------------------------------
__global__ __launch_bounds__(256) void k_dh(const float* __restrict__ H,
                                            const float* __restrict__ Dm,
                                            __bf16* __restrict__ DHf,
                                            float* __restrict__ lbe,
                                            float* __restrict__ rowsum) {
  __shared__ __bf16 HlThi[64 * 264];
  __shared__ __bf16 HlTlo[64 * 264];
  __shared__ __bf16 DHs[64 * 72];
  const int tid = threadIdx.x;
  const int t0 = blockIdx.x * 64;
  const int lane = tid & 63;
  const int wave = tid >> 6;
  const int h = lane >> 5;
  const int l31 = lane & 31;
  const float4* H4 = (const float4*)H;
#pragma unroll
  for (int r = 0; r < 16; ++r) {
    int idx = r * 256 + tid;
    int d = idx >> 4, tc = idx & 15;
    float4 v = H4[(size_t)d * (T_DIM / 4) + (t0 >> 2) + tc];
    float vv[4] = {v.x, v.y, v.z, v.w};
#pragma unroll
    for (int i = 0; i < 4; ++i) {
      __bf16 hi = (__bf16)vv[i];
      float lo = vv[i] - (float)hi;
      HlThi[(tc * 4 + i) * 264 + d] = hi;
      HlTlo[(tc * 4 + i) * 264 + d] = (__bf16)lo;
    }
  }
  __syncthreads();
  const int tt = wave & 1, nh = wave >> 1;
  const int m = tt * 32 + l31;
  const int n = nh * 32 + l31;
  f32x16 c = zero16();
  for (int kk = 0; kk < 16; ++kk) {
    bf16x8 ahi = *(const bf16x8*)&HlThi[m * 264 + kk * 16 + h * 8];
    bf16x8 alo = *(const bf16x8*)&HlTlo[m * 264 + kk * 16 + h * 8];
    const float4* dp = (const float4*)(Dm + (size_t)n * 256 + kk * 16 + h * 8);
    float4 b0 = dp[0], b1 = dp[1];
    float bv[8] = {b0.x, b0.y, b0.z, b0.w, b1.x, b1.y, b1.z, b1.w};
    bf16x8 bhi, blo;
#pragma unroll
    for (int i = 0; i < 8; ++i) {
      __bf16 hi = (__bf16)bv[i];
      bhi[i] = hi;
      blo[i] = (__bf16)(bv[i] - (float)hi);
    }
    c = __builtin_amdgcn_mfma_f32_32x32x16_bf16(ahi, bhi, c, 0, 0, 0);
    c = __builtin_amdgcn_mfma_f32_32x32x16_bf16(ahi, blo, c, 0, 0, 0);
    c = __builtin_amdgcn_mfma_f32_32x32x16_bf16(alo, bhi, c, 0, 0, 0);
  }
#pragma unroll
  for (int r = 0; r < 16; ++r) {
    int row = tt * 32 + (r & 3) + 8 * (r >> 2) + 4 * h;
    DHs[row * 72 + n] = (__bf16)c[r];
  }
  __syncthreads();
#pragma unroll
  for (int r = 0; r < 2; ++r) {
    int idx = r * 256 + tid;
    int g = idx >> 8, cc = (idx >> 5) & 7, l = idx & 31;
    bf16x8 w = *(const bf16x8*)&DHs[(g * 32 + l) * 72 + cc * 8];
    *(bf16x8*)(DHf + (size_t)(blockIdx.x * 2 + g) * 2048 + cc * 256 + l * 8) = w;
  }
  if (tid < 64) {
    float s = 0.f;
#pragma unroll
    for (int q = 0; q < 8; ++q) {
      bf16x8 w = *(const bf16x8*)&DHs[tid * 72 + q * 8];
#pragma unroll
      for (int i = 0; i < 8; ++i) { float f = (float)w[i]; s += f * f; }
    }
    lbe[t0 + tid] = -0.5f * s * LOG2E;
    rowsum[t0 + tid] = 0.f;
  }
}

// ---------------------------------------------------------------------------
// K2 v4: rowsum[t] += sum_j exp(S+lb). grid 512 x 512 threads.
//     R9 decomposition showed v3's interior ~35-40us (4x its ~10us floor):
//     the 1-deep prefetch + 4-serially-chained MFMAs + 16-exp tail is a
//     ~450cy/iter latency chain. v4: (a) two independent MFMA chains s0/s1,
//     (b) unroll-by-2 with named b0/b1 (rule-#20 safe), refill issued
//     between MFMA cluster and exp tail -> a full opposite-phase body of
//     latency cover, (c) early lbe loads. ~96+temps regs < 128 cap.
// ---------------------------------------------------------------------------
__global__ __launch_bounds__(512, 4) void k_rowsum(const __bf16* __restrict__ DHf,
                                                   const float* __restrict__ lbe,
                                                   float* __restrict__ rowsum) {
  __shared__ float red2[256][33];
  const int tid = threadIdx.x;
  const int lane = tid & 63;
  const int wave = tid >> 6;  // 0..7 = t32-group
  const int h = lane >> 5;
  const int l31 = lane & 31;
  const int t0 = (int)(blockIdx.x >> 4) * 256;
  const int jbase = (int)(blockIdx.x & 15) * 512;
  const size_t Gt = (size_t)(t0 >> 5) + wave;
  const size_t Gj0 = (size_t)(jbase >> 5);
  bf16x8 aR[4];
#pragma unroll
  for (int kk = 0; kk < 4; ++kk)
    aR[kk] = *(const bf16x8*)(DHf + Gt * 2048 + kk * 512 + lane * 8);
  float racc[16];
#pragma unroll
  for (int r = 0; r < 16; ++r) racc[r] = 0.f;
  bf16x8 b0[4], b1[4];
#pragma unroll
  for (int kk = 0; kk < 4; ++kk) {
    b0[kk] = *(const bf16x8*)(DHf + Gj0 * 2048 + kk * 512 + lane * 8);
    b1[kk] = *(const bf16x8*)(DHf + (Gj0 + 1) * 2048 + kk * 512 + lane * 8);
  }
#pragma unroll
  for (int jj = 0; jj < 8; ++jj) {
    // ---------------- even sub-iter: consume b0 (jit = 2jj) ----------------
    {
      const float lbv = lbe[jbase + (jj * 2) * 32 + l31];
      f32x16 s0 = zero16(), s1 = zero16();
      s0 = __builtin_amdgcn_mfma_f32_32x32x16_bf16(aR[0], b0[0], s0, 0, 0, 0);
      s1 = __builtin_amdgcn_mfma_f32_32x32x16_bf16(aR[1], b0[1], s1, 0, 0, 0);
      s0 = __builtin_amdgcn_mfma_f32_32x32x16_bf16(aR[2], b0[2], s0, 0, 0, 0);
      s1 = __builtin_amdgcn_mfma_f32_32x32x16_bf16(aR[3], b0[3], s1, 0, 0, 0);
      if (jj < 7) {  // refill b0 for jit = 2jj+2; covered by exp tail + odd body
        const size_t Gj = Gj0 + jj * 2 + 2;
#pragma unroll
        for (int kk = 0; kk < 4; ++kk)
          b0[kk] = *(const bf16x8*)(DHf + Gj * 2048 + kk * 512 + lane * 8);
      }
#pragma unroll
      for (int r = 0; r < 16; ++r)
        racc[r] += __builtin_amdgcn_exp2f(
            __builtin_fmaf(s0[r] + s1[r], LOG2E, lbv));
    }
    // ---------------- odd sub-iter: consume b1 (jit = 2jj+1) ---------------
    {
      const float lbv = lbe[jbase + (jj * 2 + 1) * 32 + l31];
      f32x16 s0 = zero16(), s1 = zero16();
      s0 = __builtin_amdgcn_mfma_f32_32x32x16_bf16(aR[0], b1[0], s0, 0, 0, 0);
      s1 = __builtin_amdgcn_mfma_f32_32x32x16_bf16(aR[1], b1[1], s1, 0, 0, 0);
      s0 = __builtin_amdgcn_mfma_f32_32x32x16_bf16(aR[2], b1[2], s0, 0, 0, 0);
      s1 = __builtin_amdgcn_mfma_f32_32x32x16_bf16(aR[3], b1[3], s1, 0, 0, 0);
      if (jj < 7) {  // refill b1 for jit = 2jj+3
        const size_t Gj = Gj0 + jj * 2 + 3;
#pragma unroll
        for (int kk = 0; kk < 4; ++kk)
          b1[kk] = *(const bf16x8*)(DHf + Gj * 2048 + kk * 512 + lane * 8);
      }
#pragma unroll
      for (int r = 0; r < 16; ++r)
        racc[r] += __builtin_amdgcn_exp2f(
            __builtin_fmaf(s0[r] + s1[r], LOG2E, lbv));
    }
  }
#pragma unroll
  for (int r = 0; r < 16; ++r) {
    int tl = wave * 32 + (r & 3) + 8 * (r >> 2) + 4 * h;
    red2[tl][l31] = racc[r];
  }
  __syncthreads();
  if (tid < 256) {
    float s = 0.f;
#pragma unroll 8
    for (int c = 0; c < 32; ++c) s += red2[tid][c];
    atomicAdd(&rowsum[t0 + tid], s);
  }
}

// ---------------------------------------------------------------------------
// K2b: Hbf_sw = bf16(H*rinv[t]) pre-swizzled to k_z's LDS image.
//      grid 256 x 256.  (R4-proven, byte-identical)
// ---------------------------------------------------------------------------
__global__ __launch_bounds__(256) void k_scaleH(const float* __restrict__ H,
                                                const float* __restrict__ rowsum,
                                                __bf16* __restrict__ Hbf_sw) {
  __shared__ float rinvL[64];
  const int tid = threadIdx.x;
  const int bx = blockIdx.x;
  const int tblk = bx >> 1, dh = bx & 1;
  const int t0 = tblk * 64;
  if (tid < 64) rinvL[tid] = 1.0f / rowsum[t0 + tid];
  __syncthreads();
#pragma unroll
  for (int itr = 0; itr < 4; ++itr) {
    int idx = itr * 256 + tid;
    int dl = idx >> 3, tbp = idx & 7;
    int d = dh * 128 + dl;
    int swz = (d ^ (d >> 3)) & 7;
    int tloc = (tbp ^ swz) << 3;
    const float4* hp = (const float4*)(H + (size_t)d * T_DIM + t0 + tloc);
    float4 v0 = hp[0], v1 = hp[1];
    float4 r0 = *(const float4*)&rinvL[tloc];
    float4 r1 = *(const float4*)&rinvL[tloc + 4];
    bf16x8 w;
    w[0] = (__bf16)(v0.x * r0.x); w[1] = (__bf16)(v0.y * r0.y);
    w[2] = (__bf16)(v0.z * r0.z); w[3] = (__bf16)(v0.w * r0.w);
    w[4] = (__bf16)(v1.x * r1.x); w[5] = (__bf16)(v1.y * r1.y);
    w[6] = (__bf16)(v1.z * r1.z); w[7] = (__bf16)(v1.w * r1.w);
    *(bf16x8*)(Hbf_sw + (size_t)tblk * 16384 + (size_t)d * 64 + tbp * 8) = w;
  }
}

// ---------------------------------------------------------------------------
// K3: Zp[ts][d][j] = sum_{t in slice} H'[d][t] * E[t][j].
//     R4-proven (61.4us): dbuf Hs/Pt, aR/aRn dbuf, setprio, plane stores.
//     grid 512 = 64 j-tiles(128) x 2 d-halves x 4 t-splits; 2 blk/CU.
// ---------------------------------------------------------------------------
__global__ __launch_bounds__(256, 2) void k_z(const __bf16* __restrict__ Hbf_sw,
                                              const __bf16* __restrict__ DHf,
                                              const float* __restrict__ lbe,
                                              float* __restrict__ Zp) {
  __shared__ __bf16 Hs[2][128 * 64];  // [dl][t] swizzled, 2 x 16 KB
  __shared__ __bf16 Pt[2][128 * 64];  // [j][t] swizzled,  2 x 16 KB
  const int tid = threadIdx.x;
  const int lane = tid & 63;
  const int wave = tid >> 6;
  const int h = lane >> 5;
  const int l31 = lane & 31;
  const int bx = blockIdx.x;
  const int ts = bx & 3;
  const int dh = (bx >> 2) & 1;
  const int j0 = (bx >> 3) * 128;
  const int s_tt = wave & 1, s_jg = wave >> 1;
  bf16x8 bS[2][4];
  float lbv[2];
#pragma unroll
  for (int q = 0; q < 2; ++q) {
    const size_t Gj = (j0 >> 5) + s_jg * 2 + q;
#pragma unroll
    for (int kk = 0; kk < 4; ++kk)
      bS[q][kk] = *(const bf16x8*)(DHf + Gj * 2048 + kk * 512 + lane * 8);
    lbv[q] = lbe[j0 + (s_jg * 2 + q) * 32 + l31];
  }
  f32x16 acc[2][2];
#pragma unroll
  for (int u = 0; u < 2; ++u)
#pragma unroll
    for (int v = 0; v < 2; ++v) acc[u][v] = zero16();

#define DMA_HS(buf_, it_)                                                       \
  {                                                                             \
    const __bf16* gsrc =                                                        \
        Hbf_sw + (size_t)(ts * 32 + (it_)) * 16384 + (size_t)dh * 8192;         \
    _Pragma("unroll") for (int r = 0; r < 4; ++r) {                             \
      int chunk = wave * 4 + r;                                                 \
      __builtin_amdgcn_global_load_lds(                                         \
          (const __attribute__((address_space(1))) unsigned int*)(gsrc +        \
              chunk * 512 + lane * 8),                                          \
          (__attribute__((address_space(3))) unsigned int*)(&Hs[buf_][0] +      \
              chunk * 512),                                                     \
          16, 0, 0);                                                            \
    }                                                                           \
  }

#define LOAD_AR(reg_, n_)                                                       \
  {                                                                             \
    const size_t Gt_ = (size_t)(ts * 64 + (n_)*2 + s_tt);                       \
    _Pragma("unroll") for (int kk = 0; kk < 4; ++kk)                            \
        (reg_)[kk] = *(const bf16x8*)(DHf + Gt_ * 2048 + kk * 512 + lane * 8);  \
  }

#define S_PHASE(p_, reg_)                                                       \
  {                                                                             \
    _Pragma("unroll") for (int q = 0; q < 2; ++q) {                             \
      f32x16 s = zero16();                                                      \
      _Pragma("unroll") for (int kk = 0; kk < 4; ++kk)                          \
          s = __builtin_amdgcn_mfma_f32_32x32x16_bf16((reg_)[kk], bS[q][kk], s, \
                                                      0, 0, 0);                 \
      const int jl = (s_jg * 2 + q) * 32 + l31;                                 \
      const int sj = (jl ^ (jl >> 3)) & 7;                                      \
      _Pragma("unroll") for (int g = 0; g < 4; ++g) {                           \
        const int tl = s_tt * 32 + g * 8 + 4 * h;                               \
        bf16x4 pv;                                                              \
        pv[0] = (__bf16)__builtin_amdgcn_exp2f(                                 \
            __builtin_fmaf(s[g * 4 + 0], LOG2E, lbv[q]));                       \
        pv[1] = (__bf16)__builtin_amdgcn_exp2f(                                 \
            __builtin_fmaf(s[g * 4 + 1], LOG2E, lbv[q]));                       \
        pv[2] = (__bf16)__builtin_amdgcn_exp2f(                                 \
            __builtin_fmaf(s[g * 4 + 2], LOG2E, lbv[q]));                       \
        pv[3] = (__bf16)__builtin_amdgcn_exp2f(                                 \
            __builtin_fmaf(s[g * 4 + 3], LOG2E, lbv[q]));                       \
        const int cchunk = tl >> 3;                                             \
        *(bf16x4*)&Pt[p_][jl * 64 + ((cchunk ^ sj) << 3) + 4 * h] = pv;         \
      }                                                                         \
    }                                                                           \
  }

#define Z_PHASE(p_)                                                             \
  {                                                                             \
    __builtin_amdgcn_s_setprio(1);                                              \
    _Pragma("unroll") for (int kk = 0; kk < 4; ++kk) {                          \
      const int c = kk * 2 + h;                                                 \
      bf16x8 af[2], bw[2];                                                      \
      _Pragma("unroll") for (int u = 0; u < 2; ++u) {                           \
        int dl = (wave & 1) * 64 + u * 32 + l31;                                \
        af[u] =                                                                 \
            *(const bf16x8*)&Hs[p_][dl * 64 + ((c ^ ((dl ^ (dl >> 3)) & 7)) << 3)]; \
      }                                                                         \
      _Pragma("unroll") for (int v = 0; v < 2; ++v) {                           \
        int j = (wave >> 1) * 64 + v * 32 + l31;                                \
        bw[v] =                                                                 \
            *(const bf16x8*)&Pt[p_][j * 64 + ((c ^ ((j ^ (j >> 3)) & 7)) << 3)]; \
      }                                                                         \
      _Pragma("unroll") for (int u = 0; u < 2; ++u)                             \
          _Pragma("unroll") for (int v = 0; v < 2; ++v)                         \
              acc[u][v] = __builtin_amdgcn_mfma_f32_32x32x16_bf16(              \
                  af[u], bw[v], acc[u][v], 0, 0, 0);                            \
    }                                                                           \
    __builtin_amdgcn_s_setprio(0);                                              \
  }

  bf16x8 aR[4], aRn[4];
  LOAD_AR(aR, 0);
  DMA_HS(0, 0);
  S_PHASE(0, aR);
  LOAD_AR(aRn, 1);
  __syncthreads();

  for (int ii = 0; ii < 16; ++ii) {
    const int it0 = ii * 2;
    DMA_HS(1, it0 + 1);
    if (it0 < 30) LOAD_AR(aR, it0 + 2);
    S_PHASE(1, aRn);
    Z_PHASE(0);
    __syncthreads();
    if (it0 + 1 < 31) {
      DMA_HS(0, it0 + 2);
      S_PHASE(0, aR);
    }
    if (it0 + 1 < 30) LOAD_AR(aRn, it0 + 3);
    Z_PHASE(1);
    __syncthreads();
  }
#undef Z_PHASE
#undef S_PHASE
#undef LOAD_AR
#undef DMA_HS
  // ---- epilogue: coalesced plane stores (no atomics) ----
  float* zp = Zp + (size_t)ts * (256 * (size_t)T_DIM);
#pragma unroll
  for (int u = 0; u < 2; ++u)
#pragma unroll
    for (int v = 0; v < 2; ++v)
#pragma unroll
      for (int r = 0; r < 16; ++r) {
        int d = dh * 128 + (wave & 1) * 64 + u * 32 + (r & 3) + 8 * (r >> 2) + 4 * h;
        int j = j0 + (wave >> 1) * 64 + v * 32 + l31;
        zp[(size_t)d * T_DIM + j] = acc[u][v][r];
      }
}

// ---------------------------------------------------------------------------
// K4: Z = l2 * sum_{ts=0..3} Zp[ts]. grid 2048 x 256, pure HBM-bound (~42MB).
// ---------------------------------------------------------------------------
__global__ __launch_bounds__(256) void k_zred(const float* __restrict__ Zp,
                                              const float* __restrict__ l2p,
                                              float* __restrict__ Z) {
  const int i = blockIdx.x * 256 + threadIdx.x;  // 524288 float4s total
  const float l2v = l2p[0];
  const float4* zp4 = (const float4*)Zp;
  float4 a = zp4[i];
#pragma unroll
  for (int s = 1; s < 4; ++s) {
    float4 b = zp4[(size_t)s * 524288 + i];
    a.x += b.x; a.y += b.y; a.z += b.z; a.w += b.w;
  }
  float4 o = {a.x * l2v, a.y * l2v, a.z * l2v, a.w * l2v};
  ((float4*)Z)[i] = o;
}

// ---------------------------------------------------------------------------
extern "C" void kernel_launch(void* const* d_in, const int* in_sizes, int n_in,
                              void* d_out, int out_size, void* d_ws,
                              size_t ws_size, hipStream_t stream) {
  (void)in_sizes; (void)n_in; (void)out_size; (void)ws_size;
  const float* H = (const float*)d_in[0];
  const float* Dm = (const float*)d_in[1];
  const float* l2 = (const float*)d_in[2];
  float* Z = (float*)d_out;
  char* ws = (char*)d_ws;
  __bf16* DHf = (__bf16*)ws;                        // 1,048,576 B
  float* lbe = (float*)(ws + 1048576);              // 32,768 B
  float* rowsum = (float*)(ws + 1048576 + 32768);   // 32,768 B
  __bf16* Hbf_sw = (__bf16*)(ws + 1114112);         // 4,194,304 B
  float* Zp = (float*)(ws + 5308416);               // 33,554,432 B (4 planes)

  k_dh<<<128, 256, 0, stream>>>(H, Dm, DHf, lbe, rowsum);
  k_rowsum<<<512, 512, 0, stream>>>(DHf, lbe, rowsum);
  k_scaleH<<<256, 256, 0, stream>>>(H, rowsum, Hbf_sw);
  k_z<<<512, 256, 0, stream>>>(Hbf_sw, DHf, lbe, Zp);
  k_zred<<<2048, 256, 0, stream>>>(Zp, l2, Z);
}